// Round 3
// baseline (448.640 us; speedup 1.0000x reference)
//
#include <hip/hip_runtime.h>
#include <math.h>

#define HWSZ (512*512)
#define EPSV 1e-5f

typedef _Float16 h8 __attribute__((ext_vector_type(8)));
typedef _Float16 h4 __attribute__((ext_vector_type(4)));
typedef _Float16 h2 __attribute__((ext_vector_type(2)));
typedef float    f32x4 __attribute__((ext_vector_type(4)));

__device__ __forceinline__ h8 as_h8(uint4 u) { return __builtin_bit_cast(h8, u); }
__device__ __forceinline__ uint4 as_u4(h8 v) { return __builtin_bit_cast(uint4, v); }

// ---------------------------------------------------------------------------
// NCHW fp32 -> HWC fp16. 64 px x 64 ch tile via LDS; packed u32 stores.
// ---------------------------------------------------------------------------
__global__ __launch_bounds__(256) void to_hwc_f16(const float* __restrict__ in,
                                                  unsigned* __restrict__ out32) {
    __shared__ float T[64 * 65];
    int tid = threadIdx.x;
    int pbase = blockIdx.x * 64;
    int p = tid & 63, cg = tid >> 6;
#pragma unroll
    for (int j = 0; j < 16; ++j) {
        int c = cg * 16 + j;
        T[p * 65 + c] = in[c * HWSZ + pbase + p];
    }
    __syncthreads();
    int px = tid >> 2, cb = (tid & 3) * 16;
#pragma unroll
    for (int j = 0; j < 8; ++j) {
        int c = cb + 2 * j;
        h2 v = {(_Float16)T[px * 65 + c], (_Float16)T[px * 65 + c + 1]};
        out32[(pbase + px) * 32 + (c >> 1)] = __builtin_bit_cast(unsigned, v);
    }
}

// ---------------------------------------------------------------------------
// dcn weights [o=64][c=64][3][3] fp32 -> fp16 [k][o*8 + (c8^(o&7))][c&7]
// ---------------------------------------------------------------------------
__global__ __launch_bounds__(256) void prep_dcn_w(const float* __restrict__ w,
                                                  _Float16* __restrict__ wT) {
    int i = blockIdx.x * 256 + threadIdx.x;
    if (i >= 9 * 64 * 64) return;
    int k = i / 4096, r = i % 4096;
    int o = r >> 6, c = r & 63;
    int dst = k * 4096 + (o * 8 + ((c >> 3) ^ (o & 7))) * 8 + (c & 7);
    wT[dst] = (_Float16)w[(o * 64 + c) * 9 + k];
}

// offset-conv weights [18][64][3][3] -> fp16 [k][o=32][c=64] plain (pad 0)
__global__ __launch_bounds__(256) void prep_off_w(const float* __restrict__ w,
                                                  _Float16* __restrict__ wT) {
    int i = blockIdx.x * 256 + threadIdx.x;
    if (i >= 9 * 32 * 64) return;
    int k = i / 2048, r = i % 2048;
    int o = r >> 6, c = r & 63;
    wT[k * 2048 + o * 64 + c] = (_Float16)((o < 18) ? w[(o * 64 + c) * 9 + k] : 0.f);
}

// ---------------------------------------------------------------------------
// 3x3 conv 64->18 (pad to 32) via MFMA, no LDS, no barriers.
// In: HWC fp16. Out: off[p][18] fp16. Block = 64 px (one row) x 32 n.
// ---------------------------------------------------------------------------
__global__ __launch_bounds__(256, 4) void conv3x3_off_mfma(
        const _Float16* __restrict__ in, const _Float16* __restrict__ wTo,
        const float* __restrict__ bias, _Float16* __restrict__ off) {
    int tid = threadIdx.x;
    int pbase = blockIdx.x * 64;
    int y = pbase >> 9, xblk = pbase & 511;
    int l = tid & 63, wv = tid >> 6;
    int lq = l & 15, quad = l >> 4;
    int wn = wv & 1, wm = wv >> 1;     // wave tile: 32 px x 16 n

    f32x4 zero = {0.f, 0.f, 0.f, 0.f};
    f32x4 acc[2]; acc[0] = zero; acc[1] = zero;

    for (int k = 0; k < 9; ++k) {
        int sy = y + k / 3 - 1;
        int kx = k % 3 - 1;
        bool rowok = (unsigned)sy < 512u;
        const _Float16* rowp = in + sy * (512 * 64);
#pragma unroll
        for (int kc = 0; kc < 2; ++kc) {
            h8 b = *(const h8*)(wTo + k * 2048 + (wn * 16 + lq) * 64 + kc * 32 + quad * 8);
#pragma unroll
            for (int tm = 0; tm < 2; ++tm) {
                int sx = xblk + kx + wm * 32 + tm * 16 + lq;
                h8 a = (h8)(_Float16)0.f;
                if (rowok && (unsigned)sx < 512u)
                    a = *(const h8*)(rowp + sx * 64 + kc * 32 + quad * 8);
                acc[tm] = __builtin_amdgcn_mfma_f32_16x16x32_f16(a, b, acc[tm], 0, 0, 0);
            }
        }
    }

    int n = wn * 16 + lq;
    if (n < 18) {
        float bb = bias[n];
#pragma unroll
        for (int tm = 0; tm < 2; ++tm)
#pragma unroll
            for (int reg = 0; reg < 4; ++reg) {
                int px = wm * 32 + tm * 16 + quad * 4 + reg;
                off[(pbase + px) * 18 + n] = (_Float16)(acc[tm][reg] + bb);
            }
    }
}

// ---------------------------------------------------------------------------
// Deformable conv 3x3 64->64 + bias + BN + ReLU via f16 MFMA.
// In: HWC fp16, off[p][18] fp16. Out: HWC fp16.
// ---------------------------------------------------------------------------
__global__ __launch_bounds__(256, 4) void dcn_fused(
        const _Float16* __restrict__ in, const _Float16* __restrict__ off,
        const uint4* __restrict__ wT, const float* __restrict__ bias,
        const float* __restrict__ gamma, const float* __restrict__ beta,
        const float* __restrict__ mean, const float* __restrict__ var,
        _Float16* __restrict__ out) {
    __shared__ uint4 Sl[512];        // S[px][c] fp16 swizzled
    __shared__ uint4 WLl[512];       // W[o][c]  fp16 swizzled
    __shared__ h4    SW9[9 * 64];    // bilinear weights (fp16)
    __shared__ int4  SI9[9 * 64];    // corner base indices (halves)
    __shared__ float scl_s[64], sh_s[64];

    int tid = threadIdx.x;
    int pbase = blockIdx.x * 64;

    for (int t = tid; t < 576; t += 256) {
        int p = t & 63, k = t >> 6;
        int gp = pbase + p;
        int y = gp >> 9, x = gp & 511;
        h2 dv = *(const h2*)(off + gp * 18 + 2 * k);
        float py = (float)(y + k / 3 - 1) + (float)dv[0];
        float px = (float)(x + k % 3 - 1) + (float)dv[1];
        float y0f = floorf(py), x0f = floorf(px);
        float wy = py - y0f, wx = px - x0f;
        int y0 = (int)y0f, x0 = (int)x0f;
        int y1 = y0 + 1, x1 = x0 + 1;
        float vy0 = ((unsigned)y0 < 512u) ? 1.f : 0.f;
        float vy1 = ((unsigned)y1 < 512u) ? 1.f : 0.f;
        float vx0 = ((unsigned)x0 < 512u) ? 1.f : 0.f;
        float vx1 = ((unsigned)x1 < 512u) ? 1.f : 0.f;
        h4 wg = {(_Float16)((1.f - wy) * (1.f - wx) * vy0 * vx0),
                 (_Float16)((1.f - wy) * wx * vy0 * vx1),
                 (_Float16)(wy * (1.f - wx) * vy1 * vx0),
                 (_Float16)(wy * wx * vy1 * vx1)};
        SW9[t] = wg;
        int y0c = min(max(y0, 0), 511), y1c = min(max(y1, 0), 511);
        int x0c = min(max(x0, 0), 511), x1c = min(max(x1, 0), 511);
        SI9[t] = make_int4((y0c * 512 + x0c) * 64, (y0c * 512 + x1c) * 64,
                           (y1c * 512 + x0c) * 64, (y1c * 512 + x1c) * 64);
    }
    if (tid < 64) {
        float s = gamma[tid] * rsqrtf(var[tid] + EPSV);
        scl_s[tid] = s;
        sh_s[tid] = beta[tid] - mean[tid] * s + bias[tid] * s;
    }

    int l = tid & 63, wv = tid >> 6;
    int lq = l & 15, quad = l >> 4;
    int wm = wv & 1, wn = wv >> 1;    // wave tile: 32 px x 32 oc

    f32x4 zero = {0.f, 0.f, 0.f, 0.f};
    f32x4 acc[2][2];
    acc[0][0] = zero; acc[0][1] = zero; acc[1][0] = zero; acc[1][1] = zero;

    for (int k = 0; k < 9; ++k) {
        __syncthreads();
        WLl[tid]       = wT[k * 512 + tid];
        WLl[tid + 256] = wT[k * 512 + tid + 256];
#pragma unroll
        for (int it = 0; it < 2; ++it) {
            int task = tid + 256 * it;
            int p = task >> 3, cc = task & 7;
            h4   wg = SW9[k * 64 + p];
            int4 id = SI9[k * 64 + p];
            h8 v00 = *(const h8*)(in + id.x + cc * 8);
            h8 v01 = *(const h8*)(in + id.y + cc * 8);
            h8 v10 = *(const h8*)(in + id.z + cc * 8);
            h8 v11 = *(const h8*)(in + id.w + cc * 8);
            h8 s = v00 * wg[0] + v01 * wg[1] + v10 * wg[2] + v11 * wg[3];
            Sl[p * 8 + (cc ^ (p & 7))] = as_u4(s);
        }
        __syncthreads();
#pragma unroll
        for (int kc = 0; kc < 2; ++kc) {
            int cc0 = kc * 4 + quad;
            h8 a0 = as_h8(Sl[(wm * 32 + lq) * 8 + (cc0 ^ (lq & 7))]);
            h8 a1 = as_h8(Sl[(wm * 32 + 16 + lq) * 8 + (cc0 ^ (lq & 7))]);
            h8 b0 = as_h8(WLl[(wn * 32 + lq) * 8 + (cc0 ^ (lq & 7))]);
            h8 b1 = as_h8(WLl[(wn * 32 + 16 + lq) * 8 + (cc0 ^ (lq & 7))]);
            acc[0][0] = __builtin_amdgcn_mfma_f32_16x16x32_f16(a0, b0, acc[0][0], 0, 0, 0);
            acc[0][1] = __builtin_amdgcn_mfma_f32_16x16x32_f16(a0, b1, acc[0][1], 0, 0, 0);
            acc[1][0] = __builtin_amdgcn_mfma_f32_16x16x32_f16(a1, b0, acc[1][0], 0, 0, 0);
            acc[1][1] = __builtin_amdgcn_mfma_f32_16x16x32_f16(a1, b1, acc[1][1], 0, 0, 0);
        }
    }

    float sc0 = scl_s[wn * 32 + lq],      sh0 = sh_s[wn * 32 + lq];
    float sc1 = scl_s[wn * 32 + 16 + lq], sh1 = sh_s[wn * 32 + 16 + lq];
#pragma unroll
    for (int tm = 0; tm < 2; ++tm)
#pragma unroll
        for (int reg = 0; reg < 4; ++reg) {
            int px = wm * 32 + tm * 16 + quad * 4 + reg;
            _Float16* op = out + (pbase + px) * 64 + wn * 32 + lq;
            op[0]  = (_Float16)fmaxf(fmaf(acc[tm][0][reg], sc0, sh0), 0.f);
            op[16] = (_Float16)fmaxf(fmaf(acc[tm][1][reg], sc1, sh1), 0.f);
        }
}

// ---------------------------------------------------------------------------
// 1x1 conv 64->1 + bias (fp16 HWC in, fp32 out)
// ---------------------------------------------------------------------------
__global__ __launch_bounds__(256) void conv1x1_out(const _Float16* __restrict__ in,
                                                   const float* __restrict__ w,
                                                   const float* __restrict__ b,
                                                   float* __restrict__ out) {
    int p = blockIdx.x * 256 + threadIdx.x;
    float acc = b[0];
    const h8* ip = (const h8*)(in + p * 64);
#pragma unroll
    for (int j = 0; j < 8; ++j) {
        h8 v = ip[j];
#pragma unroll
        for (int e = 0; e < 8; ++e)
            acc = fmaf((float)v[e], w[j * 8 + e], acc);
    }
    out[p] = acc;
}

// ---------------------------------------------------------------------------
extern "C" void kernel_launch(void* const* d_in, const int* in_sizes, int n_in,
                              void* d_out, int out_size, void* d_ws, size_t ws_size,
                              hipStream_t stream) {
    const float* x      = (const float*)d_in[0];
    const float* off1_w = (const float*)d_in[1];
    const float* off1_b = (const float*)d_in[2];
    const float* dcn1_w = (const float*)d_in[3];
    const float* dcn1_b = (const float*)d_in[4];
    const float* bn1_g  = (const float*)d_in[5];
    const float* bn1_be = (const float*)d_in[6];
    const float* bn1_m  = (const float*)d_in[7];
    const float* bn1_v  = (const float*)d_in[8];
    const float* off2_w = (const float*)d_in[9];
    const float* off2_b = (const float*)d_in[10];
    const float* dcn2_w = (const float*)d_in[11];
    const float* dcn2_b = (const float*)d_in[12];
    const float* bn2_g  = (const float*)d_in[13];
    const float* bn2_be = (const float*)d_in[14];
    const float* bn2_m  = (const float*)d_in[15];
    const float* bn2_v  = (const float*)d_in[16];
    const float* conv_w = (const float*)d_in[17];
    const float* conv_b = (const float*)d_in[18];
    float* out = (float*)d_out;

    char* ws = (char*)d_ws;
    _Float16* xh   = (_Float16*)ws;                       // 32 MiB (reused as h2)
    _Float16* h1   = (_Float16*)(ws + 33554432);          // 32 MiB
    _Float16* offb = (_Float16*)(ws + 2 * 33554432);      // 9 MiB
    _Float16* wT1  = (_Float16*)(ws + 2 * 33554432 + 9437184);
    _Float16* wT2  = wT1 + 36864;
    _Float16* wTo1 = wT2 + 36864;
    _Float16* wTo2 = wTo1 + 18432;
    _Float16* h2 = xh;

    prep_dcn_w<<<144, 256, 0, stream>>>(dcn1_w, wT1);
    prep_dcn_w<<<144, 256, 0, stream>>>(dcn2_w, wT2);
    prep_off_w<<<72, 256, 0, stream>>>(off1_w, wTo1);
    prep_off_w<<<72, 256, 0, stream>>>(off2_w, wTo2);
    to_hwc_f16<<<4096, 256, 0, stream>>>(x, (unsigned*)xh);

    conv3x3_off_mfma<<<4096, 256, 0, stream>>>(xh, wTo1, off1_b, offb);
    dcn_fused<<<4096, 256, 0, stream>>>(xh, offb, (const uint4*)wT1, dcn1_b,
                                        bn1_g, bn1_be, bn1_m, bn1_v, h1);
    conv3x3_off_mfma<<<4096, 256, 0, stream>>>(h1, wTo2, off2_b, offb);
    dcn_fused<<<4096, 256, 0, stream>>>(h1, offb, (const uint4*)wT2, dcn2_b,
                                        bn2_g, bn2_be, bn2_m, bn2_v, h2);
    conv1x1_out<<<1024, 256, 0, stream>>>(h2, conv_w, conv_b, out);
}

// Round 4
// 437.640 us; speedup vs baseline: 1.0251x; 1.0251x over previous
//
#include <hip/hip_runtime.h>
#include <math.h>

#define HWSZ (512*512)
#define EPSV 1e-5f

typedef _Float16 h8 __attribute__((ext_vector_type(8)));
typedef _Float16 h4 __attribute__((ext_vector_type(4)));
typedef _Float16 h2 __attribute__((ext_vector_type(2)));
typedef float    f32x4 __attribute__((ext_vector_type(4)));

__device__ __forceinline__ h8 as_h8(uint4 u) { return __builtin_bit_cast(h8, u); }
__device__ __forceinline__ uint4 as_u4(h8 v) { return __builtin_bit_cast(uint4, v); }

// ---------------------------------------------------------------------------
// NCHW fp32 -> HWC fp16. 64 px x 64 ch tile via LDS; packed u32 stores.
// ---------------------------------------------------------------------------
__global__ __launch_bounds__(256) void to_hwc_f16(const float* __restrict__ in,
                                                  unsigned* __restrict__ out32) {
    __shared__ float T[64 * 65];
    int tid = threadIdx.x;
    int pbase = blockIdx.x * 64;
    int p = tid & 63, cg = tid >> 6;
#pragma unroll
    for (int j = 0; j < 16; ++j) {
        int c = cg * 16 + j;
        T[p * 65 + c] = in[c * HWSZ + pbase + p];
    }
    __syncthreads();
    int px = tid >> 2, cb = (tid & 3) * 16;
#pragma unroll
    for (int j = 0; j < 8; ++j) {
        int c = cb + 2 * j;
        h2 v = {(_Float16)T[px * 65 + c], (_Float16)T[px * 65 + c + 1]};
        out32[(pbase + px) * 32 + (c >> 1)] = __builtin_bit_cast(unsigned, v);
    }
}

// ---------------------------------------------------------------------------
// dcn weights [o=64][c=64][3][3] fp32 -> fp16 plain [k][o][c]
// ---------------------------------------------------------------------------
__global__ __launch_bounds__(256) void prep_dcn_w(const float* __restrict__ w,
                                                  _Float16* __restrict__ wT) {
    int i = blockIdx.x * 256 + threadIdx.x;
    if (i >= 9 * 64 * 64) return;
    int k = i / 4096, r = i % 4096;
    int o = r >> 6, c = r & 63;
    wT[k * 4096 + o * 64 + c] = (_Float16)w[(o * 64 + c) * 9 + k];
}

// offset-conv weights [18][64][3][3] -> fp16 [k][o=32][c=64] plain (pad 0)
__global__ __launch_bounds__(256) void prep_off_w(const float* __restrict__ w,
                                                  _Float16* __restrict__ wT) {
    int i = blockIdx.x * 256 + threadIdx.x;
    if (i >= 9 * 32 * 64) return;
    int k = i / 2048, r = i % 2048;
    int o = r >> 6, c = r & 63;
    wT[k * 2048 + o * 64 + c] = (_Float16)((o < 18) ? w[(o * 64 + c) * 9 + k] : 0.f);
}

// ---------------------------------------------------------------------------
// 3x3 conv 64->18 (pad to 32) via MFMA. Input tile (3 rows x 66 cols x 64 ch)
// staged ONCE in LDS; all 9 taps read LDS. Block = 64 px (one row) x 32 n.
// ---------------------------------------------------------------------------
__global__ __launch_bounds__(256, 4) void conv3x3_off_mfma(
        const _Float16* __restrict__ in, const _Float16* __restrict__ wTo,
        const float* __restrict__ bias, _Float16* __restrict__ off) {
    __shared__ uint4 TILE[3 * 66 * 8];   // [row][col][chunk^swz]  (26.1 KB)

    int tid = threadIdx.x;
    int pbase = blockIdx.x * 64;
    int y = pbase >> 9, xblk = pbase & 511;

    // stage: 1584 16B tasks, coalesced, independent
    for (int t = tid; t < 1584; t += 256) {
        int row = t / 528;
        int r = t - row * 528;
        int col = r >> 3, cc = r & 7;
        int sy = y + row - 1, sx = xblk + col - 1;
        uint4 v = make_uint4(0u, 0u, 0u, 0u);
        if ((unsigned)sy < 512u && (unsigned)sx < 512u)
            v = *(const uint4*)(in + (sy * 512 + sx) * 64 + cc * 8);
        TILE[(row * 66 + col) * 8 + (cc ^ (col & 7))] = v;
    }
    __syncthreads();

    int l = tid & 63, wv = tid >> 6;
    int lq = l & 15, quad = l >> 4;
    int wn = wv & 1, wm = wv >> 1;     // wave tile: 32 px x 16 n

    f32x4 zero = {0.f, 0.f, 0.f, 0.f};
    f32x4 acc[2]; acc[0] = zero; acc[1] = zero;

#pragma unroll
    for (int k = 0; k < 9; ++k) {
        int ky = k / 3, kx = k % 3;
#pragma unroll
        for (int kc = 0; kc < 2; ++kc) {
            h8 b = *(const h8*)(wTo + k * 2048 + (wn * 16 + lq) * 64 + kc * 32 + quad * 8);
#pragma unroll
            for (int tm = 0; tm < 2; ++tm) {
                int col = kx + wm * 32 + tm * 16 + lq;     // 0..65
                int cc0 = kc * 4 + quad;
                h8 a = as_h8(TILE[(ky * 66 + col) * 8 + (cc0 ^ (col & 7))]);
                acc[tm] = __builtin_amdgcn_mfma_f32_16x16x32_f16(a, b, acc[tm], 0, 0, 0);
            }
        }
    }

    int n = wn * 16 + lq;
    if (n < 18) {
        float bb = bias[n];
#pragma unroll
        for (int tm = 0; tm < 2; ++tm)
#pragma unroll
            for (int reg = 0; reg < 4; ++reg) {
                int px = wm * 32 + tm * 16 + quad * 4 + reg;
                off[(pbase + px) * 18 + n] = (_Float16)(acc[tm][reg] + bb);
            }
    }
}

// ---------------------------------------------------------------------------
// Deformable conv 3x3 64->64 + bias + BN + ReLU via f16 MFMA.
// Double-buffered pipeline: corner gathers + B-frags for tap k+1 issue before
// the MFMA of tap k; one barrier per tap. B straight from global (L2-hot).
// ---------------------------------------------------------------------------
__global__ __launch_bounds__(256, 4) void dcn_fused(
        const _Float16* __restrict__ in, const _Float16* __restrict__ off,
        const _Float16* __restrict__ wTd, const float* __restrict__ bias,
        const float* __restrict__ gamma, const float* __restrict__ beta,
        const float* __restrict__ mean, const float* __restrict__ var,
        _Float16* __restrict__ out) {
    __shared__ uint4 Sbuf[2][512];   // S[px][c] fp16 swizzled, double-buffered
    __shared__ h4    SW9[9 * 64];
    __shared__ int4  SI9[9 * 64];
    __shared__ float scl_s[64], sh_s[64];

    int tid = threadIdx.x;
    int pbase = blockIdx.x * 64;

    // per-pixel bilinear meta for all 9 taps
    for (int t = tid; t < 576; t += 256) {
        int p = t & 63, k = t >> 6;
        int gp = pbase + p;
        int y = gp >> 9, x = gp & 511;
        h2 dv = *(const h2*)(off + gp * 18 + 2 * k);
        float py = (float)(y + k / 3 - 1) + (float)dv[0];
        float px = (float)(x + k % 3 - 1) + (float)dv[1];
        float y0f = floorf(py), x0f = floorf(px);
        float wy = py - y0f, wx = px - x0f;
        int y0 = (int)y0f, x0 = (int)x0f;
        int y1 = y0 + 1, x1 = x0 + 1;
        float vy0 = ((unsigned)y0 < 512u) ? 1.f : 0.f;
        float vy1 = ((unsigned)y1 < 512u) ? 1.f : 0.f;
        float vx0 = ((unsigned)x0 < 512u) ? 1.f : 0.f;
        float vx1 = ((unsigned)x1 < 512u) ? 1.f : 0.f;
        SW9[t] = (h4){(_Float16)((1.f - wy) * (1.f - wx) * vy0 * vx0),
                      (_Float16)((1.f - wy) * wx * vy0 * vx1),
                      (_Float16)(wy * (1.f - wx) * vy1 * vx0),
                      (_Float16)(wy * wx * vy1 * vx1)};
        int y0c = min(max(y0, 0), 511), y1c = min(max(y1, 0), 511);
        int x0c = min(max(x0, 0), 511), x1c = min(max(x1, 0), 511);
        SI9[t] = make_int4((y0c * 512 + x0c) * 64, (y0c * 512 + x1c) * 64,
                           (y1c * 512 + x0c) * 64, (y1c * 512 + x1c) * 64);
    }
    if (tid < 64) {
        float s = gamma[tid] * rsqrtf(var[tid] + EPSV);
        scl_s[tid] = s;
        sh_s[tid] = beta[tid] - mean[tid] * s + bias[tid] * s;
    }

    int l = tid & 63, wv = tid >> 6;
    int lq = l & 15, quad = l >> 4;
    int wm = wv & 1, wn = wv >> 1;      // wave tile: 32 px x 32 oc
    int p0 = tid >> 3, cc = tid & 7;    // staging task 0 (task 1: p0+32)
    int p1 = p0 + 32;

    __syncthreads();   // meta ready

    // ---- prologue: stage tap 0, load B for tap 0 ----
    {
        h4 wg = SW9[p0]; int4 id = SI9[p0];
        h8 v00 = *(const h8*)(in + id.x + cc * 8);
        h8 v01 = *(const h8*)(in + id.y + cc * 8);
        h8 v10 = *(const h8*)(in + id.z + cc * 8);
        h8 v11 = *(const h8*)(in + id.w + cc * 8);
        Sbuf[0][p0 * 8 + (cc ^ (p0 & 7))] =
            as_u4(v00 * wg[0] + v01 * wg[1] + v10 * wg[2] + v11 * wg[3]);
        wg = SW9[p1]; id = SI9[p1];
        v00 = *(const h8*)(in + id.x + cc * 8);
        v01 = *(const h8*)(in + id.y + cc * 8);
        v10 = *(const h8*)(in + id.z + cc * 8);
        v11 = *(const h8*)(in + id.w + cc * 8);
        Sbuf[0][p1 * 8 + (cc ^ (p1 & 7))] =
            as_u4(v00 * wg[0] + v01 * wg[1] + v10 * wg[2] + v11 * wg[3]);
    }
    h8 bcur[4], bnxt[4];
#pragma unroll
    for (int j = 0; j < 2; ++j)
#pragma unroll
        for (int t = 0; t < 2; ++t)
            bcur[j * 2 + t] = *(const h8*)(wTd + (wn * 32 + t * 16 + lq) * 64 + j * 32 + quad * 8);
    __syncthreads();

    f32x4 zero = {0.f, 0.f, 0.f, 0.f};
    f32x4 acc[2][2];
    acc[0][0] = zero; acc[0][1] = zero; acc[1][0] = zero; acc[1][1] = zero;

    for (int k = 0; k < 9; ++k) {
        int cur = k & 1;
        // ---- prefetch tap k+1 (issues before MFMA consumes tap k) ----
        h8 c00, c01, c10, c11, d00, d01, d10, d11;
        h4 wg0, wg1;
        if (k < 8) {
            int kk = (k + 1) * 64;
            wg0 = SW9[kk + p0]; int4 i0 = SI9[kk + p0];
            c00 = *(const h8*)(in + i0.x + cc * 8);
            c01 = *(const h8*)(in + i0.y + cc * 8);
            c10 = *(const h8*)(in + i0.z + cc * 8);
            c11 = *(const h8*)(in + i0.w + cc * 8);
            wg1 = SW9[kk + p1]; int4 i1 = SI9[kk + p1];
            d00 = *(const h8*)(in + i1.x + cc * 8);
            d01 = *(const h8*)(in + i1.y + cc * 8);
            d10 = *(const h8*)(in + i1.z + cc * 8);
            d11 = *(const h8*)(in + i1.w + cc * 8);
            const _Float16* wk = wTd + (k + 1) * 4096;
#pragma unroll
            for (int j = 0; j < 2; ++j)
#pragma unroll
                for (int t = 0; t < 2; ++t)
                    bnxt[j * 2 + t] = *(const h8*)(wk + (wn * 32 + t * 16 + lq) * 64 + j * 32 + quad * 8);
        }
        // ---- MFMA tap k ----
#pragma unroll
        for (int kc = 0; kc < 2; ++kc) {
            int cc0 = kc * 4 + quad;
            h8 a0 = as_h8(Sbuf[cur][(wm * 32 + lq) * 8 + (cc0 ^ (lq & 7))]);
            h8 a1 = as_h8(Sbuf[cur][(wm * 32 + 16 + lq) * 8 + (cc0 ^ (lq & 7))]);
            acc[0][0] = __builtin_amdgcn_mfma_f32_16x16x32_f16(a0, bcur[kc * 2 + 0], acc[0][0], 0, 0, 0);
            acc[0][1] = __builtin_amdgcn_mfma_f32_16x16x32_f16(a0, bcur[kc * 2 + 1], acc[0][1], 0, 0, 0);
            acc[1][0] = __builtin_amdgcn_mfma_f32_16x16x32_f16(a1, bcur[kc * 2 + 0], acc[1][0], 0, 0, 0);
            acc[1][1] = __builtin_amdgcn_mfma_f32_16x16x32_f16(a1, bcur[kc * 2 + 1], acc[1][1], 0, 0, 0);
        }
        // ---- blend + store tap k+1 ----
        if (k < 8) {
            Sbuf[cur ^ 1][p0 * 8 + (cc ^ (p0 & 7))] =
                as_u4(c00 * wg0[0] + c01 * wg0[1] + c10 * wg0[2] + c11 * wg0[3]);
            Sbuf[cur ^ 1][p1 * 8 + (cc ^ (p1 & 7))] =
                as_u4(d00 * wg1[0] + d01 * wg1[1] + d10 * wg1[2] + d11 * wg1[3]);
#pragma unroll
            for (int j = 0; j < 4; ++j) bcur[j] = bnxt[j];
        }
        __syncthreads();
    }

    float sc0 = scl_s[wn * 32 + lq],      sh0 = sh_s[wn * 32 + lq];
    float sc1 = scl_s[wn * 32 + 16 + lq], sh1 = sh_s[wn * 32 + 16 + lq];
#pragma unroll
    for (int tm = 0; tm < 2; ++tm)
#pragma unroll
        for (int reg = 0; reg < 4; ++reg) {
            int px = wm * 32 + tm * 16 + quad * 4 + reg;
            _Float16* op = out + (pbase + px) * 64 + wn * 32 + lq;
            op[0]  = (_Float16)fmaxf(fmaf(acc[tm][0][reg], sc0, sh0), 0.f);
            op[16] = (_Float16)fmaxf(fmaf(acc[tm][1][reg], sc1, sh1), 0.f);
        }
}

// ---------------------------------------------------------------------------
// 1x1 conv 64->1 + bias (fp16 HWC in, fp32 out)
// ---------------------------------------------------------------------------
__global__ __launch_bounds__(256) void conv1x1_out(const _Float16* __restrict__ in,
                                                   const float* __restrict__ w,
                                                   const float* __restrict__ b,
                                                   float* __restrict__ out) {
    int p = blockIdx.x * 256 + threadIdx.x;
    float acc = b[0];
    const h8* ip = (const h8*)(in + p * 64);
#pragma unroll
    for (int j = 0; j < 8; ++j) {
        h8 v = ip[j];
#pragma unroll
        for (int e = 0; e < 8; ++e)
            acc = fmaf((float)v[e], w[j * 8 + e], acc);
    }
    out[p] = acc;
}

// ---------------------------------------------------------------------------
extern "C" void kernel_launch(void* const* d_in, const int* in_sizes, int n_in,
                              void* d_out, int out_size, void* d_ws, size_t ws_size,
                              hipStream_t stream) {
    const float* x      = (const float*)d_in[0];
    const float* off1_w = (const float*)d_in[1];
    const float* off1_b = (const float*)d_in[2];
    const float* dcn1_w = (const float*)d_in[3];
    const float* dcn1_b = (const float*)d_in[4];
    const float* bn1_g  = (const float*)d_in[5];
    const float* bn1_be = (const float*)d_in[6];
    const float* bn1_m  = (const float*)d_in[7];
    const float* bn1_v  = (const float*)d_in[8];
    const float* off2_w = (const float*)d_in[9];
    const float* off2_b = (const float*)d_in[10];
    const float* dcn2_w = (const float*)d_in[11];
    const float* dcn2_b = (const float*)d_in[12];
    const float* bn2_g  = (const float*)d_in[13];
    const float* bn2_be = (const float*)d_in[14];
    const float* bn2_m  = (const float*)d_in[15];
    const float* bn2_v  = (const float*)d_in[16];
    const float* conv_w = (const float*)d_in[17];
    const float* conv_b = (const float*)d_in[18];
    float* out = (float*)d_out;

    char* ws = (char*)d_ws;
    _Float16* xh   = (_Float16*)ws;                       // 32 MiB (reused as h2)
    _Float16* h1   = (_Float16*)(ws + 33554432);          // 32 MiB
    _Float16* offb = (_Float16*)(ws + 2 * 33554432);      // 9 MiB
    _Float16* wT1  = (_Float16*)(ws + 2 * 33554432 + 9437184);
    _Float16* wT2  = wT1 + 36864;
    _Float16* wTo1 = wT2 + 36864;
    _Float16* wTo2 = wTo1 + 18432;
    _Float16* h2 = xh;

    prep_dcn_w<<<144, 256, 0, stream>>>(dcn1_w, wT1);
    prep_dcn_w<<<144, 256, 0, stream>>>(dcn2_w, wT2);
    prep_off_w<<<72, 256, 0, stream>>>(off1_w, wTo1);
    prep_off_w<<<72, 256, 0, stream>>>(off2_w, wTo2);
    to_hwc_f16<<<4096, 256, 0, stream>>>(x, (unsigned*)xh);

    conv3x3_off_mfma<<<4096, 256, 0, stream>>>(xh, wTo1, off1_b, offb);
    dcn_fused<<<4096, 256, 0, stream>>>(xh, offb, wT1, dcn1_b,
                                        bn1_g, bn1_be, bn1_m, bn1_v, h1);
    conv3x3_off_mfma<<<4096, 256, 0, stream>>>(h1, wTo2, off2_b, offb);
    dcn_fused<<<4096, 256, 0, stream>>>(h1, offb, wT2, dcn2_b,
                                        bn2_g, bn2_be, bn2_m, bn2_v, h2);
    conv1x1_out<<<1024, 256, 0, stream>>>(h2, conv_w, conv_b, out);
}

// Round 6
// 426.016 us; speedup vs baseline: 1.0531x; 1.0273x over previous
//
#include <hip/hip_runtime.h>
#include <math.h>

#define HWSZ (512*512)
#define EPSV 1e-5f

typedef _Float16 h8 __attribute__((ext_vector_type(8)));
typedef _Float16 h4 __attribute__((ext_vector_type(4)));
typedef _Float16 h2 __attribute__((ext_vector_type(2)));
typedef float    f32x4 __attribute__((ext_vector_type(4)));

__device__ __forceinline__ h8 as_h8(uint4 u) { return __builtin_bit_cast(h8, u); }
__device__ __forceinline__ uint4 as_u4(h8 v) { return __builtin_bit_cast(uint4, v); }

// ---------------------------------------------------------------------------
// NCHW fp32 -> HWC fp16. 64 px x 64 ch tile via LDS; packed u32 stores.
// ---------------------------------------------------------------------------
__global__ __launch_bounds__(256) void to_hwc_f16(const float* __restrict__ in,
                                                  unsigned* __restrict__ out32) {
    __shared__ float T[64 * 65];
    int tid = threadIdx.x;
    int pbase = blockIdx.x * 64;
    int p = tid & 63, cg = tid >> 6;
#pragma unroll
    for (int j = 0; j < 16; ++j) {
        int c = cg * 16 + j;
        T[p * 65 + c] = in[c * HWSZ + pbase + p];
    }
    __syncthreads();
    int px = tid >> 2, cb = (tid & 3) * 16;
#pragma unroll
    for (int j = 0; j < 8; ++j) {
        int c = cb + 2 * j;
        h2 v = {(_Float16)T[px * 65 + c], (_Float16)T[px * 65 + c + 1]};
        out32[(pbase + px) * 32 + (c >> 1)] = __builtin_bit_cast(unsigned, v);
    }
}

// ---------------------------------------------------------------------------
// All weight prep in one dispatch. dcn: [o][c][3][3] -> [k][o][c] fp16.
// off: [18][c][3][3] -> [k][o=32 pad][c] fp16.
// ---------------------------------------------------------------------------
__global__ __launch_bounds__(256) void prep_all(
        const float* __restrict__ dw1, const float* __restrict__ dw2,
        const float* __restrict__ ow1, const float* __restrict__ ow2,
        _Float16* __restrict__ wT1, _Float16* __restrict__ wT2,
        _Float16* __restrict__ wTo1, _Float16* __restrict__ wTo2) {
    int i = blockIdx.x * 256 + threadIdx.x;
    if (i < 36864) {
        int k = i / 4096, r = i % 4096, o = r >> 6, c = r & 63;
        wT1[k * 4096 + o * 64 + c] = (_Float16)dw1[(o * 64 + c) * 9 + k];
    } else if (i < 73728) {
        int j = i - 36864;
        int k = j / 4096, r = j % 4096, o = r >> 6, c = r & 63;
        wT2[k * 4096 + o * 64 + c] = (_Float16)dw2[(o * 64 + c) * 9 + k];
    } else if (i < 92160) {
        int j = i - 73728;
        int k = j / 2048, r = j % 2048, o = r >> 6, c = r & 63;
        wTo1[k * 2048 + o * 64 + c] = (_Float16)((o < 18) ? ow1[(o * 64 + c) * 9 + k] : 0.f);
    } else if (i < 110592) {
        int j = i - 92160;
        int k = j / 2048, r = j % 2048, o = r >> 6, c = r & 63;
        wTo2[k * 2048 + o * 64 + c] = (_Float16)((o < 18) ? ow2[(o * 64 + c) * 9 + k] : 0.f);
    }
}

// ---------------------------------------------------------------------------
// 3x3 conv 64->18 (pad 32) via MFMA. Tile (3 rows x 66 cols x 64ch) staged in
// LDS with 7 batched independent loads/thread; ALL 18 B-frags hoisted to regs
// before the barrier. After barrier: pure ds_read_b128 + MFMA.
// ---------------------------------------------------------------------------
__global__ __launch_bounds__(256, 3) void conv3x3_off_mfma(
        const _Float16* __restrict__ in, const _Float16* __restrict__ wTo,
        const float* __restrict__ bias, _Float16* __restrict__ off) {
    __shared__ uint4 TILE[3 * 66 * 8];   // 25.3 KB

    int tid = threadIdx.x;
    int pbase = blockIdx.x * 64;
    int y = pbase >> 9, xblk = pbase & 511;
    int l = tid & 63, wv = tid >> 6;
    int lq = l & 15, quad = l >> 4;
    int wn = wv & 1, wm = wv >> 1;     // wave tile: 32 px x 16 n

    // hoist all 18 B fragments (independent L2-hot loads)
    h8 breg[18];
#pragma unroll
    for (int k = 0; k < 9; ++k)
#pragma unroll
        for (int kc = 0; kc < 2; ++kc)
            breg[k * 2 + kc] = *(const h8*)(wTo + k * 2048 + (wn * 16 + lq) * 64 + kc * 32 + quad * 8);

    // stage: 1584 16B tasks, batched into 7 independent predicated loads
    uint4 v[7];
#pragma unroll
    for (int i = 0; i < 7; ++i) {
        int t = tid + 256 * i;
        int row = t / 528, r = t - row * 528;
        int col = r >> 3, cc = r & 7;
        int sy = y + row - 1, sx = xblk + col - 1;
        bool ok = (t < 1584) && ((unsigned)sy < 512u) && ((unsigned)sx < 512u);
        v[i] = ok ? *(const uint4*)(in + (sy * 512 + sx) * 64 + cc * 8)
                  : make_uint4(0u, 0u, 0u, 0u);
    }
#pragma unroll
    for (int i = 0; i < 7; ++i) {
        int t = tid + 256 * i;
        if (t < 1584) {
            int row = t / 528, r = t - row * 528;
            int col = r >> 3, cc = r & 7;
            TILE[(row * 66 + col) * 8 + (cc ^ (col & 7))] = v[i];
        }
    }
    __syncthreads();

    f32x4 zero = {0.f, 0.f, 0.f, 0.f};
    f32x4 acc[2]; acc[0] = zero; acc[1] = zero;

#pragma unroll
    for (int k = 0; k < 9; ++k) {
        int ky = k / 3, kx = k % 3;
#pragma unroll
        for (int kc = 0; kc < 2; ++kc) {
#pragma unroll
            for (int tm = 0; tm < 2; ++tm) {
                int col = kx + wm * 32 + tm * 16 + lq;
                int cc0 = kc * 4 + quad;
                h8 a = as_h8(TILE[(ky * 66 + col) * 8 + (cc0 ^ (col & 7))]);
                acc[tm] = __builtin_amdgcn_mfma_f32_16x16x32_f16(a, breg[k * 2 + kc], acc[tm], 0, 0, 0);
            }
        }
    }

    int n = wn * 16 + lq;
    if (n < 18) {
        float bb = bias[n];
#pragma unroll
        for (int tm = 0; tm < 2; ++tm)
#pragma unroll
            for (int reg = 0; reg < 4; ++reg) {
                int px = wm * 32 + tm * 16 + quad * 4 + reg;
                off[(pbase + px) * 18 + n] = (_Float16)(acc[tm][reg] + bb);
            }
    }
}

// ---------------------------------------------------------------------------
// Deformable conv 3x3 64->64 + bias + BN + ReLU via f16 MFMA.
// Depth-2 pipeline on the scattered corner gathers (issue tap k+2 at top of
// iter k). B-fragment reloads for tap k+2 issue AFTER the MFMA of tap k
// consumes that register set (WAR ordering — this was the r5 bug).
// ---------------------------------------------------------------------------
__global__ __launch_bounds__(256, 3) void dcn_fused(
        const _Float16* __restrict__ in, const _Float16* __restrict__ off,
        const _Float16* __restrict__ wTd, const float* __restrict__ bias,
        const float* __restrict__ gamma, const float* __restrict__ beta,
        const float* __restrict__ mean, const float* __restrict__ var,
        _Float16* __restrict__ out) {
    __shared__ uint4 Sbuf[2][512];   // S[px][c] fp16 swizzled, double-buffered
    __shared__ h4    SW9[9 * 64];
    __shared__ int4  SI9[9 * 64];
    __shared__ float scl_s[64], sh_s[64];

    int tid = threadIdx.x;
    int pbase = blockIdx.x * 64;

    // per-pixel bilinear meta for all 9 taps
    for (int t = tid; t < 576; t += 256) {
        int p = t & 63, k = t >> 6;
        int gp = pbase + p;
        int y = gp >> 9, x = gp & 511;
        h2 dv = *(const h2*)(off + gp * 18 + 2 * k);
        float py = (float)(y + k / 3 - 1) + (float)dv[0];
        float px = (float)(x + k % 3 - 1) + (float)dv[1];
        float y0f = floorf(py), x0f = floorf(px);
        float wy = py - y0f, wx = px - x0f;
        int y0 = (int)y0f, x0 = (int)x0f;
        int y1 = y0 + 1, x1 = x0 + 1;
        float vy0 = ((unsigned)y0 < 512u) ? 1.f : 0.f;
        float vy1 = ((unsigned)y1 < 512u) ? 1.f : 0.f;
        float vx0 = ((unsigned)x0 < 512u) ? 1.f : 0.f;
        float vx1 = ((unsigned)x1 < 512u) ? 1.f : 0.f;
        SW9[t] = (h4){(_Float16)((1.f - wy) * (1.f - wx) * vy0 * vx0),
                      (_Float16)((1.f - wy) * wx * vy0 * vx1),
                      (_Float16)(wy * (1.f - wx) * vy1 * vx0),
                      (_Float16)(wy * wx * vy1 * vx1)};
        int y0c = min(max(y0, 0), 511), y1c = min(max(y1, 0), 511);
        int x0c = min(max(x0, 0), 511), x1c = min(max(x1, 0), 511);
        SI9[t] = make_int4((y0c * 512 + x0c) * 64, (y0c * 512 + x1c) * 64,
                           (y1c * 512 + x0c) * 64, (y1c * 512 + x1c) * 64);
    }
    if (tid < 64) {
        float s = gamma[tid] * rsqrtf(var[tid] + EPSV);
        scl_s[tid] = s;
        sh_s[tid] = beta[tid] - mean[tid] * s + bias[tid] * s;
    }

    int l = tid & 63, wv = tid >> 6;
    int lq = l & 15, quad = l >> 4;
    int wm = wv & 1, wn = wv >> 1;      // wave tile: 32 px x 32 oc
    int p0 = tid >> 3, cc = tid & 7;
    int p1 = p0 + 32;

    __syncthreads();   // meta ready

    h8 setA[8], setB[8];   // corner-load register sets (even / odd taps)
    h8 bA[4], bB[4];

#define ISSUE(SET, KK) do {                                                   \
        int4 i0 = SI9[(KK) * 64 + p0];                                        \
        SET[0] = *(const h8*)(in + i0.x + cc * 8);                            \
        SET[1] = *(const h8*)(in + i0.y + cc * 8);                            \
        SET[2] = *(const h8*)(in + i0.z + cc * 8);                            \
        SET[3] = *(const h8*)(in + i0.w + cc * 8);                            \
        int4 i1 = SI9[(KK) * 64 + p1];                                        \
        SET[4] = *(const h8*)(in + i1.x + cc * 8);                            \
        SET[5] = *(const h8*)(in + i1.y + cc * 8);                            \
        SET[6] = *(const h8*)(in + i1.z + cc * 8);                            \
        SET[7] = *(const h8*)(in + i1.w + cc * 8);                            \
    } while (0)

#define BLEND(SET, KK, BUF) do {                                              \
        h4 w0 = SW9[(KK) * 64 + p0];                                          \
        Sbuf[BUF][p0 * 8 + (cc ^ (p0 & 7))] =                                 \
            as_u4(SET[0] * w0[0] + SET[1] * w0[1] + SET[2] * w0[2] + SET[3] * w0[3]); \
        h4 w1 = SW9[(KK) * 64 + p1];                                          \
        Sbuf[BUF][p1 * 8 + (cc ^ (p1 & 7))] =                                 \
            as_u4(SET[4] * w1[0] + SET[5] * w1[1] + SET[6] * w1[2] + SET[7] * w1[3]); \
    } while (0)

#define LOADB(BS, KK) do {                                                    \
        const _Float16* wk = wTd + (KK) * 4096;                               \
        BS[0] = *(const h8*)(wk + (wn * 32 + lq) * 64 + quad * 8);            \
        BS[1] = *(const h8*)(wk + (wn * 32 + 16 + lq) * 64 + quad * 8);       \
        BS[2] = *(const h8*)(wk + (wn * 32 + lq) * 64 + 32 + quad * 8);       \
        BS[3] = *(const h8*)(wk + (wn * 32 + 16 + lq) * 64 + 32 + quad * 8);  \
    } while (0)

    // prologue: corner loads for taps 0,1 in flight; B for taps 0,1 resident
    ISSUE(setA, 0);
    ISSUE(setB, 1);
    LOADB(bA, 0);
    LOADB(bB, 1);
    BLEND(setA, 0, 0);
    __syncthreads();

    f32x4 zero = {0.f, 0.f, 0.f, 0.f};
    f32x4 acc[2][2];
    acc[0][0] = zero; acc[0][1] = zero; acc[1][0] = zero; acc[1][1] = zero;

#pragma unroll
    for (int k = 0; k < 9; ++k) {
        int cur = k & 1;
        // corner gathers for tap k+2 (longest-latency, deepest prefetch);
        // their register set (parity k) was blended last iteration -> free
        if (k < 7) {
            if ((k & 1) == 0) ISSUE(setA, k + 2);
            else              ISSUE(setB, k + 2);
        }
        // MFMA tap k (consumes b-set of parity k)
        {
            const h8* bc = (k & 1) ? bB : bA;
#pragma unroll
            for (int kc = 0; kc < 2; ++kc) {
                int cc0 = kc * 4 + quad;
                h8 a0 = as_h8(Sbuf[cur][(wm * 32 + lq) * 8 + (cc0 ^ (lq & 7))]);
                h8 a1 = as_h8(Sbuf[cur][(wm * 32 + 16 + lq) * 8 + (cc0 ^ (lq & 7))]);
                acc[0][0] = __builtin_amdgcn_mfma_f32_16x16x32_f16(a0, bc[kc * 2 + 0], acc[0][0], 0, 0, 0);
                acc[0][1] = __builtin_amdgcn_mfma_f32_16x16x32_f16(a0, bc[kc * 2 + 1], acc[0][1], 0, 0, 0);
                acc[1][0] = __builtin_amdgcn_mfma_f32_16x16x32_f16(a1, bc[kc * 2 + 0], acc[1][0], 0, 0, 0);
                acc[1][1] = __builtin_amdgcn_mfma_f32_16x16x32_f16(a1, bc[kc * 2 + 1], acc[1][1], 0, 0, 0);
            }
        }
        // NOW the b-set of parity k is free: reload it for tap k+2
        if (k < 7) {
            if ((k & 1) == 0) LOADB(bA, k + 2);
            else              LOADB(bB, k + 2);
        }
        // blend tap k+1 (corner loads issued one full iteration ago)
        if (k < 8) {
            if (((k + 1) & 1) == 0) BLEND(setA, k + 1, cur ^ 1);
            else                    BLEND(setB, k + 1, cur ^ 1);
            __syncthreads();
        }
    }
#undef ISSUE
#undef BLEND
#undef LOADB

    float sc0 = scl_s[wn * 32 + lq],      sh0 = sh_s[wn * 32 + lq];
    float sc1 = scl_s[wn * 32 + 16 + lq], sh1 = sh_s[wn * 32 + 16 + lq];
#pragma unroll
    for (int tm = 0; tm < 2; ++tm)
#pragma unroll
        for (int reg = 0; reg < 4; ++reg) {
            int px = wm * 32 + tm * 16 + quad * 4 + reg;
            _Float16* op = out + (pbase + px) * 64 + wn * 32 + lq;
            op[0]  = (_Float16)fmaxf(fmaf(acc[tm][0][reg], sc0, sh0), 0.f);
            op[16] = (_Float16)fmaxf(fmaf(acc[tm][1][reg], sc1, sh1), 0.f);
        }
}

// ---------------------------------------------------------------------------
// 1x1 conv 64->1 + bias (fp16 HWC in, fp32 out)
// ---------------------------------------------------------------------------
__global__ __launch_bounds__(256) void conv1x1_out(const _Float16* __restrict__ in,
                                                   const float* __restrict__ w,
                                                   const float* __restrict__ b,
                                                   float* __restrict__ out) {
    int p = blockIdx.x * 256 + threadIdx.x;
    float acc = b[0];
    const h8* ip = (const h8*)(in + p * 64);
#pragma unroll
    for (int j = 0; j < 8; ++j) {
        h8 v = ip[j];
#pragma unroll
        for (int e = 0; e < 8; ++e)
            acc = fmaf((float)v[e], w[j * 8 + e], acc);
    }
    out[p] = acc;
}

// ---------------------------------------------------------------------------
extern "C" void kernel_launch(void* const* d_in, const int* in_sizes, int n_in,
                              void* d_out, int out_size, void* d_ws, size_t ws_size,
                              hipStream_t stream) {
    const float* x      = (const float*)d_in[0];
    const float* off1_w = (const float*)d_in[1];
    const float* off1_b = (const float*)d_in[2];
    const float* dcn1_w = (const float*)d_in[3];
    const float* dcn1_b = (const float*)d_in[4];
    const float* bn1_g  = (const float*)d_in[5];
    const float* bn1_be = (const float*)d_in[6];
    const float* bn1_m  = (const float*)d_in[7];
    const float* bn1_v  = (const float*)d_in[8];
    const float* off2_w = (const float*)d_in[9];
    const float* off2_b = (const float*)d_in[10];
    const float* dcn2_w = (const float*)d_in[11];
    const float* dcn2_b = (const float*)d_in[12];
    const float* bn2_g  = (const float*)d_in[13];
    const float* bn2_be = (const float*)d_in[14];
    const float* bn2_m  = (const float*)d_in[15];
    const float* bn2_v  = (const float*)d_in[16];
    const float* conv_w = (const float*)d_in[17];
    const float* conv_b = (const float*)d_in[18];
    float* out = (float*)d_out;

    char* ws = (char*)d_ws;
    _Float16* xh   = (_Float16*)ws;                       // 32 MiB (reused as h2)
    _Float16* h1   = (_Float16*)(ws + 33554432);          // 32 MiB
    _Float16* offb = (_Float16*)(ws + 2 * 33554432);      // 9 MiB
    _Float16* wT1  = (_Float16*)(ws + 2 * 33554432 + 9437184);
    _Float16* wT2  = wT1 + 36864;
    _Float16* wTo1 = wT2 + 36864;
    _Float16* wTo2 = wTo1 + 18432;
    _Float16* h2 = xh;

    prep_all<<<432, 256, 0, stream>>>(dcn1_w, dcn2_w, off1_w, off2_w,
                                      wT1, wT2, wTo1, wTo2);
    to_hwc_f16<<<4096, 256, 0, stream>>>(x, (unsigned*)xh);

    conv3x3_off_mfma<<<4096, 256, 0, stream>>>(xh, wTo1, off1_b, offb);
    dcn_fused<<<4096, 256, 0, stream>>>(xh, offb, wT1, dcn1_b,
                                        bn1_g, bn1_be, bn1_m, bn1_v, h1);
    conv3x3_off_mfma<<<4096, 256, 0, stream>>>(h1, wTo2, off2_b, offb);
    dcn_fused<<<4096, 256, 0, stream>>>(h1, offb, wT2, dcn2_b,
                                        bn2_g, bn2_be, bn2_m, bn2_v, h2);
    conv1x1_out<<<1024, 256, 0, stream>>>(h2, conv_w, conv_b, out);
}